// Round 3
// baseline (197.419 us; speedup 1.0000x reference)
//
#include <hip/hip_runtime.h>

namespace {

constexpr int HW    = 512 * 512;
constexpr int NBATCH = 4;
constexpr int NPIX  = NBATCH * HW;      // 1,048,576
constexpr int NCLS  = 26;
constexpr float EPS = 1e-8f;

__global__ __launch_bounds__(64) void hiera_zero(float* __restrict__ acc) {
  if (threadIdx.x < 3) acc[threadIdx.x] = 0.0f;
}

__global__ __launch_bounds__(256) void hiera_main(
    const float* __restrict__ logits, const int* __restrict__ labels,
    float* __restrict__ acc) {
  // acc[0] = pre-scaled BCE sum, acc[1] = CE sum, acc[2] = valid count
  constexpr int LP[20] = {0,0,0,1,1,1,2,2,2,3,3,3,4,4,4,5,5,5,5,5};

  float a_bce = 0.0f, a_ce = 0.0f, a_vd = 0.0f;
  const int ngroups = NPIX / 4;
  const int stride  = gridDim.x * blockDim.x;

  for (int g = blockIdx.x * blockDim.x + threadIdx.x; g < ngroups; g += stride) {
    const int p0 = g << 2;
    const int b  = p0 / HW;            // groups of 4 never straddle a batch
    const int hw = p0 - b * HW;
    const float* base = logits + (size_t)b * NCLS * HW + hw;

    // Load 26 channels x 4 pixels, apply sigmoid in place.
    float4 x[NCLS];
#pragma unroll
    for (int c = 0; c < NCLS; ++c) {
      float4 v = *reinterpret_cast<const float4*>(base + (size_t)c * HW);
      v.x = 1.0f / (1.0f + __expf(-v.x));
      v.y = 1.0f / (1.0f + __expf(-v.y));
      v.z = 1.0f / (1.0f + __expf(-v.z));
      v.w = 1.0f / (1.0f + __expf(-v.w));
      x[c] = v;
    }
    const int4 lb = *reinterpret_cast<const int4*>(labels + p0);

#pragma unroll
    for (int j = 0; j < 4; ++j) {
      const int L = (j == 0) ? lb.x : (j == 1) ? lb.y : (j == 2) ? lb.z : lb.w;
      float pr[NCLS];
#pragma unroll
      for (int c = 0; c < NCLS; ++c)
        pr[c] = (j == 0) ? x[c].x : (j == 1) ? x[c].y : (j == 2) ? x[c].z : x[c].w;

      const bool valid = (L != 26);

      // ---- leaf set (k = 20) ----
      float cmax[6] = {0.f, 0.f, 0.f, 0.f, 0.f, 0.f};  // probs > 0, so 0-init ok
      float bce_l = 0.0f, se_l = 0.0f, sel_l = 0.0f;
      int parL = -1;
#pragma unroll
      for (int i = 0; i < 20; ++i) {
        const int lp = LP[i];
        const float m  = pr[6 + i];                 // mcma_leaf
        const float mc = fminf(m, pr[lp]);          // mcla_leaf
        cmax[lp] = fmaxf(cmax[lp], m);
        const bool lab = (L == 6 + i);
        // lab in {0,1}: bce = lab ? -log(mcla+eps) : -log(1-mcma+eps)
        bce_l -= __logf(lab ? (mc + EPS) : (1.0f - m + EPS));
        se_l  += __expf(m);                         // mcma in (0,1): no max-shift needed
        sel_l  = lab ? m : sel_l;
        parL   = lab ? lp : parL;
      }
      const float lse_l = __logf(se_l);

      // ---- parent set (k = 6) ----
      float bce_p = 0.0f, se_p = 0.0f, sel_p = 0.0f;
#pragma unroll
      for (int p = 0; p < 6; ++p) {
        const float mm = fmaxf(pr[p], cmax[p]);     // mcma_par
        const bool lab = (L == p) || (parL == p);   // exactly one true when valid
        bce_p -= __logf(lab ? (pr[p] + EPS) : (1.0f - mm + EPS));
        se_p  += __expf(mm);
        sel_p  = lab ? mm : sel_p;
      }
      const float lse_p = __logf(se_p);

      if (valid) {
        a_vd  += 1.0f;
        a_bce += bce_l * (1.0f / 20.0f) + bce_p * (1.0f / 6.0f);
        a_ce  += lse_p - sel_p;                     // parent CE (one hot label)
        if (L >= 6) a_ce += lse_l - sel_l;          // leaf CE only if label is a leaf
      }
      // invalid pixels: lab==0 everywhere -> all BCE terms 0; still count in CE mean
      // (handled by dividing by NPIX in finalize)
    }
  }

  // ---- block reduction: wave shuffle -> LDS -> atomics ----
  const int lane = threadIdx.x & 63;
  const int wid  = threadIdx.x >> 6;
#pragma unroll
  for (int off = 32; off > 0; off >>= 1) {
    a_bce += __shfl_down(a_bce, off);
    a_ce  += __shfl_down(a_ce,  off);
    a_vd  += __shfl_down(a_vd,  off);
  }
  __shared__ float sred[3][4];
  if (lane == 0) { sred[0][wid] = a_bce; sred[1][wid] = a_ce; sred[2][wid] = a_vd; }
  __syncthreads();
  if (threadIdx.x == 0) {
    atomicAdd(&acc[0], sred[0][0] + sred[0][1] + sred[0][2] + sred[0][3]);
    atomicAdd(&acc[1], sred[1][0] + sred[1][1] + sred[1][2] + sred[1][3]);
    atomicAdd(&acc[2], sred[2][0] + sred[2][1] + sred[2][2] + sred[2][3]);
  }
}

__global__ __launch_bounds__(64) void hiera_final(const float* __restrict__ acc,
                                                  float* __restrict__ out) {
  if (threadIdx.x == 0) {
    const float loss = acc[0] / acc[2];             // already scaled by 1/20, 1/6
    const float ce   = acc[1] * (1.0f / (float)NPIX);
    out[0] = 5.0f * loss + ce;
  }
}

}  // namespace

extern "C" void kernel_launch(void* const* d_in, const int* in_sizes, int n_in,
                              void* d_out, int out_size, void* d_ws, size_t ws_size,
                              hipStream_t stream) {
  const float* logits = (const float*)d_in[0];
  const int*   labels = (const int*)d_in[1];
  float* acc = (float*)d_ws;   // 3 floats
  float* out = (float*)d_out;

  hiera_zero<<<1, 64, 0, stream>>>(acc);
  // 262144 groups of 4 pixels; 1024 blocks x 256 threads covers it exactly.
  hiera_main<<<1024, 256, 0, stream>>>(logits, labels, acc);
  hiera_final<<<1, 64, 0, stream>>>(acc, out);
}